// Round 5
// baseline (270.776 us; speedup 1.0000x reference)
//
#include <hip/hip_runtime.h>
#include <stdint.h>

typedef unsigned short u16;
typedef __attribute__((ext_vector_type(8))) __bf16 bf16x8;
typedef __attribute__((ext_vector_type(4))) float f32x4;
typedef __attribute__((ext_vector_type(16))) float f32x16;
typedef __attribute__((ext_vector_type(4))) u16 u16x4;
typedef __attribute__((ext_vector_type(4))) uint32_t u32x4;
typedef __attribute__((ext_vector_type(2))) uint32_t u32x2;

__device__ __forceinline__ u16 f2bf(float f) {
    union { float f; uint32_t u; } v; v.f = f;
    uint32_t r = (v.u + 0x7fffu + ((v.u >> 16) & 1u)) >> 16;
    return (u16)r;
}

__device__ __forceinline__ void gll16(const u16* g, u16* l) {
    __builtin_amdgcn_global_load_lds((const __attribute__((address_space(1))) uint32_t*)g,
                                     (__attribute__((address_space(3))) uint32_t*)l, 16, 0, 0);
}

// ---------------- cast fp32 -> bf16 (x) ----------------
__global__ void cast_kernel(const float* __restrict__ in, u16* __restrict__ out, int n) {
    int i = (blockIdx.x * blockDim.x + threadIdx.x) * 4;
    if (i + 3 < n) {
        float4 v = *(const float4*)(in + i);
        u16x4 o;
        o.x = f2bf(v.x); o.y = f2bf(v.y); o.z = f2bf(v.z); o.w = f2bf(v.w);
        *(u16x4*)(out + i) = o;
    }
}

// ---------------- cast + transpose: in[R][C] fp32 -> out[C][R] bf16 ----------------
__global__ void transpose_cast(const float* __restrict__ in, u16* __restrict__ out, int R, int C) {
    __shared__ float tile[32][33];
    int c0 = blockIdx.x * 32;
    int r0 = blockIdx.y * 32;
    int tx = threadIdx.x, ty = threadIdx.y;   // 32 x 8
#pragma unroll
    for (int i = 0; i < 32; i += 8)
        tile[ty + i][tx] = in[(size_t)(r0 + ty + i) * C + c0 + tx];
    __syncthreads();
#pragma unroll
    for (int i = 0; i < 32; i += 8)
        out[(size_t)(c0 + ty + i) * R + r0 + tx] = f2bf(tile[tx][ty + i]);
}

// ---------------- GEMM: C[M,N] = A[M,K](bf16) * Bt[N,K](bf16)^T + bias ----------------
// Round 1: fixed latency-bound gemm_bt with (a) single barrier per K-step via
// async double-buffered gll16, (b) vtr aliasing the staging buffers (LDS
// 53K->36K, 4 blocks/CU), (c) XOR swizzle via pre-swizzled global source.
// Result: 90.8us -> out of top-5.
template <int EPI>
__global__ __launch_bounds__(256) void gemm_bt(
    const u16* __restrict__ A, const u16* __restrict__ Bt,
    int K, int N, const float* __restrict__ bias,
    u16* __restrict__ Qb, u16* __restrict__ Kb, u16* __restrict__ Vtb,
    float* __restrict__ Cout)
{
    __shared__ __align__(16) u16 smem[EPI == 0 ? 18432 : 16384];

    const int tid  = threadIdx.x;
    const int lane = tid & 63;
    const int wave = tid >> 6;
    const int wm = (wave >> 1) * 64;
    const int wn = (wave & 1) * 64;
    const int l15 = lane & 15;
    const int l4  = lane >> 4;
    const int bm = blockIdx.x * 128;
    const int bn = blockIdx.y * 128;

    f32x4 acc[4][4];
#pragma unroll
    for (int i = 0; i < 4; i++)
#pragma unroll
        for (int j = 0; j < 4; j++)
            acc[i][j] = (f32x4){0.f, 0.f, 0.f, 0.f};

    const int r0 = tid >> 2;
    const int u0 = (tid & 3) ^ ((r0 >> 1) & 3);       // swizzled source unit
    const u16* Ap = A + (size_t)(bm + r0) * K + u0 * 8;
    const u16* Bp = Bt + (size_t)(bn + r0) * K + u0 * 8;
    const int su = (l15 >> 1) & 3;                     // fragment-read swizzle

    auto stage = [&](int k0, int pb) {
        u16* dst = smem + pb * 8192 + wave * 512;
        gll16(Ap + k0, dst);
        gll16(Ap + (size_t)64 * K + k0, dst + 2048);
        gll16(Bp + k0, dst + 4096);
        gll16(Bp + (size_t)64 * K + k0, dst + 6144);
    };

    stage(0, 0);
    __syncthreads();

    int p = 0;
    for (int k0 = 0; k0 < K; k0 += 32) {
        if (k0 + 32 < K) stage(k0 + 32, p ^ 1);

        const u16* AsP = smem + p * 8192;
        const u16* BsP = AsP + 4096;

        bf16x8 af[4];
#pragma unroll
        for (int mi = 0; mi < 4; mi++)
            af[mi] = *(const bf16x8*)&AsP[(wm + mi * 16 + l15) * 32 + ((l4 ^ su) * 8)];
#pragma unroll
        for (int ni = 0; ni < 4; ni++) {
            bf16x8 bf = *(const bf16x8*)&BsP[(wn + ni * 16 + l15) * 32 + ((l4 ^ su) * 8)];
#pragma unroll
            for (int mi = 0; mi < 4; mi++)
                acc[mi][ni] = __builtin_amdgcn_mfma_f32_16x16x32_bf16(af[mi], bf, acc[mi][ni], 0, 0, 0);
        }

        __syncthreads();
        p ^= 1;
    }

    if (EPI == 0 && blockIdx.y >= 16) {
        u16* tr = smem + wave * (64 * 72);
#pragma unroll
        for (int mi = 0; mi < 4; mi++)
#pragma unroll
            for (int ni = 0; ni < 4; ni++)
#pragma unroll
                for (int r = 0; r < 4; r++) {
                    int d  = ni * 16 + l15;
                    int tl = mi * 16 + l4 * 4 + r;
                    int gn = bn + wn + ni * 16 + l15;
                    tr[d * 72 + tl] = f2bf(acc[mi][ni][r] + bias[gn]);
                }
        __syncthreads();
        const int hh = (bn + wn - 2048) >> 6;
        const int bb = (bm + wm) >> 11;
        const int tglob0 = (bm + wm) & 2047;
        const int t0 = (lane & 7) * 8;
#pragma unroll
        for (int it = 0; it < 8; it++) {
            int d = it * 8 + (lane >> 3);
            uint4 v = *(const uint4*)&tr[d * 72 + t0];
            *(uint4*)(Vtb + (((size_t)(bb * 16 + hh)) * 64 + d) * 2048 + tglob0 + t0) = v;
        }
        return;
    }

#pragma unroll
    for (int mi = 0; mi < 4; mi++) {
#pragma unroll
        for (int ni = 0; ni < 4; ni++) {
#pragma unroll
            for (int r = 0; r < 4; r++) {
                int gm = bm + wm + mi * 16 + l4 * 4 + r;
                int gn = bn + wn + ni * 16 + l15;
                float v = acc[mi][ni][r] + bias[gn];
                if (EPI == 0) {
                    int s = gn >> 10, rem = gn & 1023;
                    int h = rem >> 6, d = rem & 63;
                    int b = gm >> 11, t = gm & 2047;
                    size_t qkidx = (((size_t)(b * 16 + h)) * 2048 + t) * 64 + d;
                    if (s == 0)      Qb[qkidx] = f2bf(v * 0.125f);
                    else             Kb[qkidx] = f2bf(v);
                } else {
                    Cout[(size_t)gm * N + gn] = v;
                }
            }
        }
    }
}

// ---------------- flash attention (causal), S^T formulation, 32x32 MFMA ----------------
// Round 4 post-mortem: 32x32 refactor failed correctness; full offline audit
// localizes the bug to the permlane32_swap exchange direction (only
// unverifiable step; L-combine was direction-invariant so it couldn't catch
// it). Round 5: SAME 32x32 structure, but the P->PV exchange is eliminated
// entirely. P stays lane-local: the PV B-operand consumes P exactly as the
// QK^T D-layout left it (slot j of half hl holds kv (j&3)+8*(j>>2)+4*hl),
// and the matching fixed permutation sigma is absorbed into the V^T
// A-operand read: slot group = two 4-col groups [b0,b0+4)+[b0+8,b0+12),
// b0 = s*32+f*16+4*hl -> two ds_read_b64 per V fragment. Zero cross-lane
// ops in the loop; final L reduction via proven __shfl_xor(.,32).
// Per 64-kv tile per wave vs round 3: DS ops 48 -> 24 (8 b128 + 16 b64),
// MFMA 36 -> 16 (L-mfma deleted), same 32KB dbuf staging / single barrier.
__global__ __launch_bounds__(256, 4) void attn_kernel(
    const u16* __restrict__ Qb, const u16* __restrict__ Kb,
    const u16* __restrict__ Vtb, u16* __restrict__ Ob)
{
    const int blk = blockIdx.x;
    const int qb  = 15 - (blk >> 6);
    const int bh  = blk & 63;
    const int b   = bh >> 4;
    const int hd  = bh & 15;
    const u16* Qh = Qb + ((size_t)bh) * 2048 * 64;
    const u16* Kh = Kb + ((size_t)bh) * 2048 * 64;
    const u16* Vh = Vtb + ((size_t)bh) * 64 * 2048;

    __shared__ __align__(16) u16 KsBuf[2][4096];   // 64kv x 64d, macro-swizzled
    __shared__ __align__(16) u16 VsBuf[2][4096];   // 64d x 64kv, macro-swizzled

    const int tid  = threadIdx.x;
    const int wave = tid >> 6;
    const int lane = tid & 63;
    const int l31  = lane & 31;
    const int hl   = lane >> 5;

    const int qrow0 = qb * 128 + wave * 32;
    const int nt = 2 * (qb + 1);          // 64-wide kv tiles

    // async-stage kv tile j: K 64x64 (512 16B units) + V 64x64 (512 units);
    // 2+2 gll16/thread. LDS unit lu linear; global source pre-swizzled:
    // u = (lu&15) ^ (mr&15), row = 2*mr + (u>>3), col-unit = u&7.
    // (audited: stage<->read round-trip bijective; staging 128B-coalesced)
    auto stage = [&](int j, int pb) {
#pragma unroll
        for (int i = 0; i < 2; i++) {
            int lu = i * 256 + tid;               // 0..511
            int mr = lu >> 4;
            int u  = (lu & 15) ^ (mr & 15);
            int rr = mr * 2 + (u >> 3), uc = u & 7;
            gll16(Kh + ((size_t)(j * 64 + rr)) * 64 + uc * 8,
                  &KsBuf[pb][(i * 256 + wave * 64) * 8]);
            gll16(Vh + (size_t)rr * 2048 + j * 64 + uc * 8,
                  &VsBuf[pb][(i * 256 + wave * 64) * 8]);
        }
    };

    // Q B-frags (32x32x16): lane holds Q[q=l31][d = c*16 + hl*8 + j]
    bf16x8 qf[4];
#pragma unroll
    for (int c = 0; c < 4; c++)
        qf[c] = *(const bf16x8*)(Qh + (size_t)(qrow0 + l31) * 64 + c * 16 + hl * 8);

    f32x16 Ot[2];                          // O^T[d=dblk*32+rows][q=l31]
#pragma unroll
    for (int dblk = 0; dblk < 2; dblk++)
#pragma unroll
        for (int r = 0; r < 16; r++)
            Ot[dblk][r] = 0.f;
    float la[4] = {0.f, 0.f, 0.f, 0.f};    // L partial sums (per-lane)

    stage(0, 0);
    __syncthreads();

    int p = 0;
    for (int j = 0; j < nt; ++j) {
        if (j + 1 < nt) stage(j + 1, p ^ 1);   // async; lands during compute

        const u16* Kc = KsBuf[p];
        const u16* Vc = VsBuf[p];
        const int kvb = j * 64 - qb * 128;     // >=0 only on the 2 diag tiles
        const bool diag = (kvb >= 0);
        const int qq = wave * 32 + l31;        // local q of this lane
        const bool skip = diag && (kvb > wave * 32 + 31);  // wave fully masked

        if (!skip) {
#pragma unroll
            for (int s = 0; s < 2; s++) {      // 32-kv sub-block
                // S^T = sum_d K*Q^T over 4 d-chunks of 16
                f32x16 S;
#pragma unroll
                for (int r = 0; r < 16; r++) S[r] = 0.f;
                const int kv_l = s * 32 + l31;
                const int mrK  = kv_l >> 1;
                const int ubK  = ((kv_l & 1) << 3) + hl;
#pragma unroll
                for (int c = 0; c < 4; c++) {
                    bf16x8 kf = *(const bf16x8*)&Kc[((mrK << 4) + ((ubK + c * 2) ^ (mrK & 15))) << 3];
                    S = __builtin_amdgcn_mfma_f32_32x32x16_bf16(kf, qf[c], S, 0, 0, 0);
                }

                // sigma-permuted V^T A-frags, issued early (overlap exp):
                // frag (dblk,f) slot j holds V^T[dd][s*32+f*16+(j&3)+8*(j>>2)+4hl]
                // = cols [b0,b0+4) (lo b64) and [b0+8,b0+12) (hi b64),
                // b0 = s*32+f*16+4hl -> units (4s+2f), (4s+2f+1), byte +8hl.
                u32x2 vl[2][2], vh[2][2];
                const int dd0 = l31;            // dblk adds 32
#pragma unroll
                for (int dblk = 0; dblk < 2; dblk++) {
                    int dd  = dblk * 32 + dd0;
                    int mrV = dd >> 1;
                    int ubV = (dd & 1) << 3;
#pragma unroll
                    for (int f = 0; f < 2; f++) {
                        int uc0 = 4 * s + 2 * f;
                        vl[dblk][f] = *(const u32x2*)&Vc[(((mrV << 4) + ((ubV + uc0) ^ (mrV & 15))) << 3) + hl * 4];
                        vh[dblk][f] = *(const u32x2*)&Vc[(((mrV << 4) + ((ubV + uc0 + 1) ^ (mrV & 15))) << 3) + hl * 4];
                    }
                }

                // mask + exp + L accumulation (row of reg r: (r&3)+8*(r>>2)+4hl)
                float pr[16];
#pragma unroll
                for (int r = 0; r < 16; r++) {
                    float sv = S[r];
                    if (diag) {
                        int kvloc = s * 32 + (r & 3) + 8 * (r >> 2) + 4 * hl;
                        if (kvb + kvloc > qq) sv = -__builtin_inff();
                    }
                    pr[r] = __expf(sv);
                    la[r & 3] += pr[r];
                }

                // pack neighbor pairs (v_perm truncation, proven numerics);
                // word t = (bf16(pr[2t]) lo, bf16(pr[2t+1]) hi)
                uint32_t w[8];
#pragma unroll
                for (int t = 0; t < 8; t++) {
                    union { float fv; uint32_t u; } e0, e1;
                    e0.fv = pr[2 * t]; e1.fv = pr[2 * t + 1];
                    w[t] = __builtin_amdgcn_perm(e1.u, e0.u, 0x07060302u);
                }

                // PV: B-operand = P as-is (slot j = pr[8f+j]); A = sigma-V
#pragma unroll
                for (int f = 0; f < 2; f++) {
                    bf16x8 ptf = __builtin_bit_cast(bf16x8,
                        (u32x4){w[4 * f + 0], w[4 * f + 1], w[4 * f + 2], w[4 * f + 3]});
#pragma unroll
                    for (int dblk = 0; dblk < 2; dblk++) {
                        bf16x8 vtf = __builtin_bit_cast(bf16x8,
                            (u32x4){vl[dblk][f].x, vl[dblk][f].y, vh[dblk][f].x, vh[dblk][f].y});
                        Ot[dblk] = __builtin_amdgcn_mfma_f32_32x32x16_bf16(vtf, ptf, Ot[dblk], 0, 0, 0);
                    }
                }
            }
        }

        __syncthreads();   // drains the async stage (vmcnt 0) + flips buffer
        p ^= 1;
    }

    // L: this lane holds half the kv-sum for column q=l31; partner (l^32)
    // holds the other half. One shfl_xor (proven semantics) combines.
    float Lh = (la[0] + la[1]) + (la[2] + la[3]);
    float Lo = __shfl_xor(Lh, 32);
    float inv = 1.0f / (Lh + Lo);

    const int tq = qrow0 + l31;
#pragma unroll
    for (int dblk = 0; dblk < 2; dblk++)
#pragma unroll
        for (int g = 0; g < 4; g++) {
            u16x4 o;
            o.x = f2bf(Ot[dblk][g * 4 + 0] * inv);
            o.y = f2bf(Ot[dblk][g * 4 + 1] * inv);
            o.z = f2bf(Ot[dblk][g * 4 + 2] * inv);
            o.w = f2bf(Ot[dblk][g * 4 + 3] * inv);
            *(u16x4*)(Ob + ((size_t)(b * 2048 + tq)) * 1024 + hd * 64 + dblk * 32 + g * 8 + hl * 4) = o;
        }
}

extern "C" void kernel_launch(void* const* d_in, const int* in_sizes, int n_in,
                              void* d_out, int out_size, void* d_ws, size_t ws_size,
                              hipStream_t stream) {
    const float* x     = (const float*)d_in[0];
    const float* w_qkv = (const float*)d_in[1];
    const float* b_qkv = (const float*)d_in[2];
    const float* w_out = (const float*)d_in[3];
    const float* b_out = (const float*)d_in[4];
    float* out = (float*)d_out;

    size_t off = 0;
    char* ws = (char*)d_ws;
    auto alloc = [&](size_t bytes) -> void* {
        void* p = ws + off;
        off += (bytes + 255) & ~(size_t)255;
        return p;
    };
    u16* xb    = (u16*)alloc((size_t)8192 * 1024 * 2);
    u16* wqkvT = (u16*)alloc((size_t)3072 * 1024 * 2);
    u16* woutT = (u16*)alloc((size_t)1024 * 1024 * 2);
    u16* Qb    = (u16*)alloc((size_t)8192 * 1024 * 2);   // [B,H,T,Dh]
    u16* Kb    = (u16*)alloc((size_t)8192 * 1024 * 2);   // [B,H,T,Dh]
    u16* Vtb   = (u16*)alloc((size_t)8192 * 1024 * 2);   // [B,H,Dh,T]
    u16* Ob    = xb;  // reuse x_bf16 after GEMM1 consumed it

    cast_kernel<<<dim3(8192), dim3(256), 0, stream>>>(x, xb, 8192 * 1024);
    transpose_cast<<<dim3(3072 / 32, 1024 / 32), dim3(32, 8), 0, stream>>>(w_qkv, wqkvT, 1024, 3072);
    transpose_cast<<<dim3(1024 / 32, 1024 / 32), dim3(32, 8), 0, stream>>>(w_out, woutT, 1024, 1024);

    gemm_bt<0><<<dim3(64, 24), dim3(256), 0, stream>>>(xb, wqkvT, 1024, 3072, b_qkv, Qb, Kb, Vtb, nullptr);
    attn_kernel<<<dim3(1024), dim3(256), 0, stream>>>(Qb, Kb, Vtb, Ob);
    gemm_bt<1><<<dim3(64, 8), dim3(256), 0, stream>>>(Ob, woutT, 1024, 1024, b_out, nullptr, nullptr, nullptr, out);
}

// Round 6
// 250.388 us; speedup vs baseline: 1.0814x; 1.0814x over previous
//
#include <hip/hip_runtime.h>
#include <stdint.h>

typedef unsigned short u16;
typedef __attribute__((ext_vector_type(8))) __bf16 bf16x8;
typedef __attribute__((ext_vector_type(4))) float f32x4;
typedef __attribute__((ext_vector_type(4))) u16 u16x4;
typedef __attribute__((ext_vector_type(4))) uint32_t u32x4;

__device__ __forceinline__ u16 f2bf(float f) {
    union { float f; uint32_t u; } v; v.f = f;
    uint32_t r = (v.u + 0x7fffu + ((v.u >> 16) & 1u)) >> 16;
    return (u16)r;
}

__device__ __forceinline__ void gll16(const u16* g, u16* l) {
    __builtin_amdgcn_global_load_lds((const __attribute__((address_space(1))) uint32_t*)g,
                                     (__attribute__((address_space(3))) uint32_t*)l, 16, 0, 0);
}

// ---------------- fused prep: cast x (blocks 0..8191), transpose+cast w_qkv
// (blocks 8192..11263), transpose+cast w_out (blocks 11264..12287) ----------------
// Round 6: rounds 1-5 totals show ~50-70us of inter-kernel gap across 6
// launches (Sum(dispatch dur) ~182us vs 252.6 total at round 3). Fusing the
// three prep kernels into one launch removes 2 boundaries. Per-phase code is
// byte-identical to the proven cast_kernel / transpose_cast.
__global__ __launch_bounds__(256) void prep_kernel(
    const float* __restrict__ x, u16* __restrict__ xb,
    const float* __restrict__ w_qkv, u16* __restrict__ wqkvT,
    const float* __restrict__ w_out, u16* __restrict__ woutT)
{
    const int bid = blockIdx.x;
    const int tid = threadIdx.x;
    if (bid < 8192) {                     // ---- cast x: fp32 -> bf16 ----
        int i = (bid * 256 + tid) * 4;
        float4 v = *(const float4*)(x + i);
        u16x4 o;
        o.x = f2bf(v.x); o.y = f2bf(v.y); o.z = f2bf(v.z); o.w = f2bf(v.w);
        *(u16x4*)(xb + i) = o;
        return;
    }
    // ---- transpose+cast: in[R][C] fp32 -> out[C][R] bf16 ----
    __shared__ float tile[32][33];
    const float* in; u16* out; int C, bx, by;
    const int b2 = bid - 8192;
    if (b2 < 3072) { in = w_qkv; out = wqkvT; C = 3072; bx = b2 % 96; by = b2 / 96; }
    else           { int b3 = b2 - 3072;
                     in = w_out; out = woutT; C = 1024; bx = b3 % 32; by = b3 / 32; }
    const int R = 1024;
    const int c0 = bx * 32, r0 = by * 32;
    const int tx = tid & 31, ty = tid >> 5;   // 32 x 8
#pragma unroll
    for (int i = 0; i < 32; i += 8)
        tile[ty + i][tx] = in[(size_t)(r0 + ty + i) * C + c0 + tx];
    __syncthreads();
#pragma unroll
    for (int i = 0; i < 32; i += 8)
        out[(size_t)(c0 + ty + i) * R + r0 + tx] = f2bf(tile[tx][ty + i]);
}

// ---------------- GEMM: C[M,N] = A[M,K](bf16) * Bt[N,K](bf16)^T + bias ----------------
// Round 1: fixed latency-bound gemm_bt with (a) single barrier per K-step via
// async double-buffered gll16, (b) vtr aliasing the staging buffers (LDS
// 53K->36K, 4 blocks/CU), (c) XOR swizzle via pre-swizzled global source.
// Result: 90.8us -> out of top-5.
template <int EPI>
__global__ __launch_bounds__(256) void gemm_bt(
    const u16* __restrict__ A, const u16* __restrict__ Bt,
    int K, int N, const float* __restrict__ bias,
    u16* __restrict__ Qb, u16* __restrict__ Kb, u16* __restrict__ Vtb,
    float* __restrict__ Cout)
{
    __shared__ __align__(16) u16 smem[EPI == 0 ? 18432 : 16384];

    const int tid  = threadIdx.x;
    const int lane = tid & 63;
    const int wave = tid >> 6;
    const int wm = (wave >> 1) * 64;
    const int wn = (wave & 1) * 64;
    const int l15 = lane & 15;
    const int l4  = lane >> 4;
    const int bm = blockIdx.x * 128;
    const int bn = blockIdx.y * 128;

    f32x4 acc[4][4];
#pragma unroll
    for (int i = 0; i < 4; i++)
#pragma unroll
        for (int j = 0; j < 4; j++)
            acc[i][j] = (f32x4){0.f, 0.f, 0.f, 0.f};

    const int r0 = tid >> 2;
    const int u0 = (tid & 3) ^ ((r0 >> 1) & 3);       // swizzled source unit
    const u16* Ap = A + (size_t)(bm + r0) * K + u0 * 8;
    const u16* Bp = Bt + (size_t)(bn + r0) * K + u0 * 8;
    const int su = (l15 >> 1) & 3;                     // fragment-read swizzle

    auto stage = [&](int k0, int pb) {
        u16* dst = smem + pb * 8192 + wave * 512;
        gll16(Ap + k0, dst);
        gll16(Ap + (size_t)64 * K + k0, dst + 2048);
        gll16(Bp + k0, dst + 4096);
        gll16(Bp + (size_t)64 * K + k0, dst + 6144);
    };

    stage(0, 0);
    __syncthreads();

    int p = 0;
    for (int k0 = 0; k0 < K; k0 += 32) {
        if (k0 + 32 < K) stage(k0 + 32, p ^ 1);

        const u16* AsP = smem + p * 8192;
        const u16* BsP = AsP + 4096;

        bf16x8 af[4];
#pragma unroll
        for (int mi = 0; mi < 4; mi++)
            af[mi] = *(const bf16x8*)&AsP[(wm + mi * 16 + l15) * 32 + ((l4 ^ su) * 8)];
#pragma unroll
        for (int ni = 0; ni < 4; ni++) {
            bf16x8 bf = *(const bf16x8*)&BsP[(wn + ni * 16 + l15) * 32 + ((l4 ^ su) * 8)];
#pragma unroll
            for (int mi = 0; mi < 4; mi++)
                acc[mi][ni] = __builtin_amdgcn_mfma_f32_16x16x32_bf16(af[mi], bf, acc[mi][ni], 0, 0, 0);
        }

        __syncthreads();
        p ^= 1;
    }

    if (EPI == 0 && blockIdx.y >= 16) {
        u16* tr = smem + wave * (64 * 72);
#pragma unroll
        for (int mi = 0; mi < 4; mi++)
#pragma unroll
            for (int ni = 0; ni < 4; ni++)
#pragma unroll
                for (int r = 0; r < 4; r++) {
                    int d  = ni * 16 + l15;
                    int tl = mi * 16 + l4 * 4 + r;
                    int gn = bn + wn + ni * 16 + l15;
                    tr[d * 72 + tl] = f2bf(acc[mi][ni][r] + bias[gn]);
                }
        __syncthreads();
        const int hh = (bn + wn - 2048) >> 6;
        const int bb = (bm + wm) >> 11;
        const int tglob0 = (bm + wm) & 2047;
        const int t0 = (lane & 7) * 8;
#pragma unroll
        for (int it = 0; it < 8; it++) {
            int d = it * 8 + (lane >> 3);
            uint4 v = *(const uint4*)&tr[d * 72 + t0];
            *(uint4*)(Vtb + (((size_t)(bb * 16 + hh)) * 64 + d) * 2048 + tglob0 + t0) = v;
        }
        return;
    }

#pragma unroll
    for (int mi = 0; mi < 4; mi++) {
#pragma unroll
        for (int ni = 0; ni < 4; ni++) {
#pragma unroll
            for (int r = 0; r < 4; r++) {
                int gm = bm + wm + mi * 16 + l4 * 4 + r;
                int gn = bn + wn + ni * 16 + l15;
                float v = acc[mi][ni][r] + bias[gn];
                if (EPI == 0) {
                    int s = gn >> 10, rem = gn & 1023;
                    int h = rem >> 6, d = rem & 63;
                    int b = gm >> 11, t = gm & 2047;
                    size_t qkidx = (((size_t)(b * 16 + h)) * 2048 + t) * 64 + d;
                    if (s == 0)      Qb[qkidx] = f2bf(v * 0.125f);
                    else             Kb[qkidx] = f2bf(v);
                } else {
                    Cout[(size_t)gm * N + gn] = v;
                }
            }
        }
    }
}

// ---------------- flash attention (causal), S^T formulation ----------------
// Round 5 post-mortem: the 32x32 zero-exchange variant regressed (92us) —
// WRITE_SIZE doubled (8B store chunks < 32B HBM sector -> 2x write + RMW
// fetch) and the single-32q-stream lost ILP; VALU busy-time (~35us) is the
// conserved cost across all variants. REVERTED to the round-3 proven 74.5us
// kernel: 16x16 MFMA, KVB=64 dbuf gll16 staging (32KB, 4 blocks/CU), XOR
// swizzles, bpermute P-redistribution, 32B-chunk epilogue.
__global__ __launch_bounds__(256) void attn_kernel(
    const u16* __restrict__ Qb, const u16* __restrict__ Kb,
    const u16* __restrict__ Vtb, u16* __restrict__ Ob)
{
    const int blk = blockIdx.x;
    const int qb  = 15 - (blk >> 6);
    const int bh  = blk & 63;
    const int b   = bh >> 4;
    const int h   = bh & 15;
    const u16* Qh = Qb + ((size_t)bh) * 2048 * 64;
    const u16* Kh = Kb + ((size_t)bh) * 2048 * 64;
    const u16* Vh = Vtb + ((size_t)bh) * 64 * 2048;

    __shared__ __align__(16) u16 KsBuf[2][64 * 64];   // swizzled
    __shared__ __align__(16) u16 VsBuf[2][64 * 64];   // swizzled

    const int tid  = threadIdx.x;
    const int wave = tid >> 6;
    const int lane = tid & 63;
    const int l15 = lane & 15;
    const int l4  = lane >> 4;

    // bpermute source byte-addresses (fixed permutation)
    const int addr_a = (((l4 & 1) * 32) + l15) * 4;
    const int addr_b = addr_a + 64;
    const bool hi_t  = (l4 & 2) != 0;

    const bf16x8 ones = __builtin_bit_cast(bf16x8,
        (u32x4){0x3F803F80u, 0x3F803F80u, 0x3F803F80u, 0x3F803F80u});

    const int qrow0 = qb * 128 + wave * 32;
    const int nt = 2 * (qb + 1);          // 64-wide kv tiles

    // async-stage kv tile j (64 rows K + 64 cols V) into buffer pb
    auto stage = [&](int j, int pb) {
#pragma unroll
        for (int i = 0; i < 2; i++) {
            int lu = i * 256 + tid;               // unit index 0..511
            int r = lu >> 3, u = (lu & 7) ^ (r & 7);
            gll16(Kh + ((size_t)(j * 64 + r)) * 64 + u * 8,
                  &KsBuf[pb][(i * 256 + wave * 64) * 8]);
            gll16(Vh + (size_t)r * 2048 + j * 64 + u * 8,
                  &VsBuf[pb][(i * 256 + wave * 64) * 8]);
        }
    };

    // Q B-frags: B[n=q][k=d]
    bf16x8 qf[2][2];
#pragma unroll
    for (int mi = 0; mi < 2; mi++)
#pragma unroll
        for (int kd = 0; kd < 2; kd++)
            qf[mi][kd] = *(const bf16x8*)(Qh + (size_t)(qrow0 + mi * 16 + l15) * 64 + kd * 32 + l4 * 8);

    f32x4 Ot[4][2];   // [d-tile][q-tile]
#pragma unroll
    for (int md = 0; md < 4; md++)
#pragma unroll
        for (int mi = 0; mi < 2; mi++)
            Ot[md][mi] = (f32x4){0.f, 0.f, 0.f, 0.f};
    f32x4 L[2];
    L[0] = (f32x4){0.f, 0.f, 0.f, 0.f};
    L[1] = (f32x4){0.f, 0.f, 0.f, 0.f};

    stage(0, 0);
    __syncthreads();   // compiler drains vmcnt(0) first

    int p = 0;
    for (int j = 0; j < nt; ++j) {
        if (j + 1 < nt) stage(j + 1, p ^ 1);   // fully async; lands during compute

        const u16* Kc = KsBuf[p];
        const u16* Vc = VsBuf[p];
        const int kvb = j * 64 - qb * 128;     // >=0 only on the 2 diag tiles
        const bool diag = (kvb >= 0);

        // Fused per 32-kv chunk: S^T (K*Q^T) -> exp -> pack -> bpermute -> PV
#pragma unroll
        for (int kk = 0; kk < 2; kk++) {
            uint32_t pk[2][2][2];   // [tt][mi][pair]
#pragma unroll
            for (int tt = 0; tt < 2; tt++) {
                const int t = kk * 2 + tt;
                const int rr = t * 16 + l15;
                f32x4 St[2];
                St[0] = (f32x4){0.f, 0.f, 0.f, 0.f};
                St[1] = (f32x4){0.f, 0.f, 0.f, 0.f};
#pragma unroll
                for (int kd = 0; kd < 2; kd++) {
                    bf16x8 kf = *(const bf16x8*)&Kc[((rr << 3) + ((kd * 4 + l4) ^ (rr & 7))) * 8];
                    St[0] = __builtin_amdgcn_mfma_f32_16x16x32_bf16(kf, qf[0][kd], St[0], 0, 0, 0);
                    St[1] = __builtin_amdgcn_mfma_f32_16x16x32_bf16(kf, qf[1][kd], St[1], 0, 0, 0);
                }
#pragma unroll
                for (int mi = 0; mi < 2; mi++) {
                    int qloc = wave * 32 + mi * 16 + l15;
                    float pr[4];
#pragma unroll
                    for (int r = 0; r < 4; r++) {
                        float s = St[mi][r];
                        if (diag) {
                            int kvloc = kvb + t * 16 + l4 * 4 + r;
                            if (kvloc > qloc) s = -__builtin_inff();
                        }
                        pr[r] = __expf(s);
                    }
                    union { float f; uint32_t u; } u0, u1, u2, u3;
                    u0.f = pr[0]; u1.f = pr[1]; u2.f = pr[2]; u3.f = pr[3];
                    pk[tt][mi][0] = __builtin_amdgcn_perm(u1.u, u0.u, 0x07060302u);
                    pk[tt][mi][1] = __builtin_amdgcn_perm(u3.u, u2.u, 0x07060302u);
                }
            }

            bf16x8 vtf[4];
#pragma unroll
            for (int md = 0; md < 4; md++) {
                const int rr = md * 16 + l15;
                vtf[md] = *(const bf16x8*)&Vc[((rr << 3) + ((kk * 4 + l4) ^ (rr & 7))) * 8];
            }
#pragma unroll
            for (int mi = 0; mi < 2; mi++) {
                uint32_t s0a = __builtin_amdgcn_ds_bpermute(addr_a, pk[0][mi][0]);
                uint32_t s0b = __builtin_amdgcn_ds_bpermute(addr_a, pk[1][mi][0]);
                uint32_t s1a = __builtin_amdgcn_ds_bpermute(addr_a, pk[0][mi][1]);
                uint32_t s1b = __builtin_amdgcn_ds_bpermute(addr_a, pk[1][mi][1]);
                uint32_t s2a = __builtin_amdgcn_ds_bpermute(addr_b, pk[0][mi][0]);
                uint32_t s2b = __builtin_amdgcn_ds_bpermute(addr_b, pk[1][mi][0]);
                uint32_t s3a = __builtin_amdgcn_ds_bpermute(addr_b, pk[0][mi][1]);
                uint32_t s3b = __builtin_amdgcn_ds_bpermute(addr_b, pk[1][mi][1]);
                u32x4 pt;
                pt.x = hi_t ? s0b : s0a;
                pt.y = hi_t ? s1b : s1a;
                pt.z = hi_t ? s2b : s2a;
                pt.w = hi_t ? s3b : s3a;
                bf16x8 ptf = __builtin_bit_cast(bf16x8, pt);
#pragma unroll
                for (int md = 0; md < 4; md++)
                    Ot[md][mi] = __builtin_amdgcn_mfma_f32_16x16x32_bf16(vtf[md], ptf, Ot[md][mi], 0, 0, 0);
                L[mi] = __builtin_amdgcn_mfma_f32_16x16x32_bf16(ones, ptf, L[mi], 0, 0, 0);
            }
        }

        __syncthreads();   // drains the async stage (vmcnt 0) + flips buffer
        p ^= 1;
    }

    // epilogue: O^T/l -> Ob[B*T, 1024]; pack 4 consecutive d -> 8B store
#pragma unroll
    for (int mi = 0; mi < 2; mi++) {
        float inv = 1.0f / L[mi][0];
        int t = qrow0 + mi * 16 + l15;
#pragma unroll
        for (int md = 0; md < 4; md++) {
            u16x4 o;
            o.x = f2bf(Ot[md][mi][0] * inv);
            o.y = f2bf(Ot[md][mi][1] * inv);
            o.z = f2bf(Ot[md][mi][2] * inv);
            o.w = f2bf(Ot[md][mi][3] * inv);
            *(u16x4*)(Ob + ((size_t)(b * 2048 + t)) * 1024 + h * 64 + md * 16 + l4 * 4) = o;
        }
    }
}

extern "C" void kernel_launch(void* const* d_in, const int* in_sizes, int n_in,
                              void* d_out, int out_size, void* d_ws, size_t ws_size,
                              hipStream_t stream) {
    const float* x     = (const float*)d_in[0];
    const float* w_qkv = (const float*)d_in[1];
    const float* b_qkv = (const float*)d_in[2];
    const float* w_out = (const float*)d_in[3];
    const float* b_out = (const float*)d_in[4];
    float* out = (float*)d_out;

    size_t off = 0;
    char* ws = (char*)d_ws;
    auto alloc = [&](size_t bytes) -> void* {
        void* p = ws + off;
        off += (bytes + 255) & ~(size_t)255;
        return p;
    };
    u16* xb    = (u16*)alloc((size_t)8192 * 1024 * 2);
    u16* wqkvT = (u16*)alloc((size_t)3072 * 1024 * 2);
    u16* woutT = (u16*)alloc((size_t)1024 * 1024 * 2);
    u16* Qb    = (u16*)alloc((size_t)8192 * 1024 * 2);   // [B,H,T,Dh]
    u16* Kb    = (u16*)alloc((size_t)8192 * 1024 * 2);   // [B,H,T,Dh]
    u16* Vtb   = (u16*)alloc((size_t)8192 * 1024 * 2);   // [B,H,Dh,T]
    u16* Ob    = xb;  // reuse x_bf16 after GEMM1 consumed it

    prep_kernel<<<dim3(8192 + 3072 + 1024), dim3(256), 0, stream>>>(
        x, xb, w_qkv, wqkvT, w_out, woutT);
    gemm_bt<0><<<dim3(64, 24), dim3(256), 0, stream>>>(xb, wqkvT, 1024, 3072, b_qkv, Qb, Kb, Vtb, nullptr);
    attn_kernel<<<dim3(1024), dim3(256), 0, stream>>>(Qb, Kb, Vtb, Ob);
    gemm_bt<1><<<dim3(64, 8), dim3(256), 0, stream>>>(Ob, woutT, 1024, 1024, b_out, nullptr, nullptr, nullptr, out);
}